// Round 13
// baseline (257.432 us; speedup 1.0000x reference)
//
#include <hip/hip_runtime.h>

// ---------------------------------------------------------------------------
// GCN: x1 = relu(Ahat @ (fts@W1) + b1); x2 = relu(Ahat @ (x1@W2) + b2);
//      out = x2@Wc + bc.  Ahat = D^-1/2 (A + I) D^-1/2.
// d_out = [out (N*16) | x2 (N*128)] fp32.
// R2-R13: scan/gather/MFMA/slot-capture/8-replica/fma_mix ladder.
// R10,R14/15,R18/19,R20 FAILED: every attempt to beat the HW scheduler
//      with static partitions or manual prefetch regressed. Lesson learned.
// R16/R17: NPW=4 (agg2) / NPW=1 (agg1). 257.0us.
// R21: merged scan via atomic block-ticket (row_beg/row_end, non-monotone
//      bases). 253.3us BEST.
// R22: independent-kernel overlap by block-range fusion. gemm1 depends only
//      on Bsw1 (prep), NOT on the graph build -- but the stream serializes.
//      k_cg = count-blocks || gemm1-half-A; k_fg = fill-blocks || gemm1-
//      half-B. To break gemm1's dinv dependency, layer-1 xwb is UNSCALED;
//      agg1 applies dinv[src] as the fma_mix scale operand (same instr
//      count; accum8's scale slot was 1.0f) and di on the self term.
//      Launches 9 -> 7. Count/fill (atomic-latency-bound) overlap with
//      MFMA/stream-bound gemm halves -- complementary resources.
// ---------------------------------------------------------------------------

#define IN_DIM 256
#define HID 128
#define OUT_DIM 16
#define SCAN_B 256
#define NREP 8

typedef _Float16 half8  __attribute__((ext_vector_type(8)));
typedef float    floatx4 __attribute__((ext_vector_type(4)));

// acc[0..7] += s * fp16 elements of u (4 dwords, lo/hi halves), exact fma.
__device__ __forceinline__ void accum8(float* acc, uint4 u, float s) {
    asm("v_fma_mix_f32 %0, %1, %2, %0 op_sel:[0,0,0] op_sel_hi:[1,0,0]"
        : "+v"(acc[0]) : "v"(u.x), "v"(s));
    asm("v_fma_mix_f32 %0, %1, %2, %0 op_sel:[1,0,0] op_sel_hi:[1,0,0]"
        : "+v"(acc[1]) : "v"(u.x), "v"(s));
    asm("v_fma_mix_f32 %0, %1, %2, %0 op_sel:[0,0,0] op_sel_hi:[1,0,0]"
        : "+v"(acc[2]) : "v"(u.y), "v"(s));
    asm("v_fma_mix_f32 %0, %1, %2, %0 op_sel:[1,0,0] op_sel_hi:[1,0,0]"
        : "+v"(acc[3]) : "v"(u.y), "v"(s));
    asm("v_fma_mix_f32 %0, %1, %2, %0 op_sel:[0,0,0] op_sel_hi:[1,0,0]"
        : "+v"(acc[4]) : "v"(u.z), "v"(s));
    asm("v_fma_mix_f32 %0, %1, %2, %0 op_sel:[1,0,0] op_sel_hi:[1,0,0]"
        : "+v"(acc[5]) : "v"(u.z), "v"(s));
    asm("v_fma_mix_f32 %0, %1, %2, %0 op_sel:[0,0,0] op_sel_hi:[1,0,0]"
        : "+v"(acc[6]) : "v"(u.w), "v"(s));
    asm("v_fma_mix_f32 %0, %1, %2, %0 op_sel:[1,0,0] op_sel_hi:[1,0,0]"
        : "+v"(acc[7]) : "v"(u.w), "v"(s));
}

__device__ __forceinline__ void wswz_one(const float* W, _Float16* Bsw, int o, int permK) {
    int j    = o & 7;
    int lane = (o >> 3) & 63;
    int t    = (o >> 9) & 7;
    int c    = o >> 12;
    int k = c * 32 + ((lane >> 4) << 3) + j;
    if (permK) k = ((k & 7) << 4) + (k >> 3);
    int ncol = t * 16 + (lane & 15);
    Bsw[o] = (_Float16)W[k * 128 + ncol];
}

// Fused prep: zero rep planes + ticket; swizzle W1,W2; permute biases.
__global__ void k_prep(int* __restrict__ rep, int nrepN, int* __restrict__ gtick,
                       const float* __restrict__ W1, _Float16* __restrict__ Bsw1,
                       const float* __restrict__ W2, _Float16* __restrict__ Bsw2,
                       const float* __restrict__ b1, float* __restrict__ bp1,
                       const float* __restrict__ b2, float* __restrict__ bp2) {
    int t = blockIdx.x * blockDim.x + threadIdx.x;
    if (t == 0) gtick[0] = 0;
    int z4 = nrepN >> 2;
    int zr = z4 + (nrepN & 3);
    if (t < z4) { ((int4*)rep)[t] = make_int4(0, 0, 0, 0); return; }
    if (t < zr) { rep[4 * z4 + (t - z4)] = 0; return; }
    int o = t - zr;
    if (o < IN_DIM * HID) { wswz_one(W1, Bsw1, o, 0); return; }
    o -= IN_DIM * HID;
    if (o < HID * HID) { wswz_one(W2, Bsw2, o, 1); return; }
    o -= HID * HID;
    if (o < HID) { bp1[o] = b1[((o & 7) << 4) + (o >> 3)]; return; }
    o -= HID;
    if (o < HID) { bp2[o] = b2[((o & 7) << 4) + (o >> 3)]; return; }
}

// ---- device bodies for block-range fusion (R22) ----

__device__ __forceinline__ void count_body(int blk, int tid,
                                           const int* __restrict__ dst,
                                           int* __restrict__ rep,
                                           int* __restrict__ slot,
                                           int nN, int e8, int e) {
    int i = blk * 256 + tid;
    if (i < e8) {
        int4 d0 = ((const int4*)dst)[2 * i];
        int4 d1 = ((const int4*)dst)[2 * i + 1];
        int4 s0, s1;
        s0.x = atomicAdd(&rep[0 * nN + d0.x], 1);
        s0.y = atomicAdd(&rep[1 * nN + d0.y], 1);
        s0.z = atomicAdd(&rep[2 * nN + d0.z], 1);
        s0.w = atomicAdd(&rep[3 * nN + d0.w], 1);
        s1.x = atomicAdd(&rep[4 * nN + d1.x], 1);
        s1.y = atomicAdd(&rep[5 * nN + d1.y], 1);
        s1.z = atomicAdd(&rep[6 * nN + d1.z], 1);
        s1.w = atomicAdd(&rep[7 * nN + d1.w], 1);
        ((int4*)slot)[2 * i]     = s0;
        ((int4*)slot)[2 * i + 1] = s1;
    }
    int base = e8 * 8;
    int t = blk * 256 + tid;
    if (t < e - base) {
        int j = base + t;
        slot[j] = atomicAdd(&rep[(j & 7) * nN + dst[j]], 1);
    }
}

__device__ __forceinline__ void fill_body(int blk, int tid,
                                          const int* __restrict__ src,
                                          const int* __restrict__ dst,
                                          const int* __restrict__ slot,
                                          const int* __restrict__ rep,
                                          int* __restrict__ col,
                                          int nN, int e8, int e) {
    int i = blk * 256 + tid;
    if (i < e8) {
        int4 v0 = ((const int4*)src)[2 * i];
        int4 v1 = ((const int4*)src)[2 * i + 1];
        int4 d0 = ((const int4*)dst)[2 * i];
        int4 d1 = ((const int4*)dst)[2 * i + 1];
        int4 s0 = ((const int4*)slot)[2 * i];
        int4 s1 = ((const int4*)slot)[2 * i + 1];
        col[rep[0 * nN + d0.x] + s0.x] = v0.x;
        col[rep[1 * nN + d0.y] + s0.y] = v0.y;
        col[rep[2 * nN + d0.z] + s0.z] = v0.z;
        col[rep[3 * nN + d0.w] + s0.w] = v0.w;
        col[rep[4 * nN + d1.x] + s1.x] = v1.x;
        col[rep[5 * nN + d1.y] + s1.y] = v1.y;
        col[rep[6 * nN + d1.z] + s1.z] = v1.z;
        col[rep[7 * nN + d1.w] + s1.w] = v1.w;
    }
    int base = e8 * 8;
    int t = blk * 256 + tid;
    if (t < e - base) {
        int j = base + t;
        col[rep[(j & 7) * nN + dst[j]] + slot[j]] = src[j];
    }
}

// Cb[n,128](fp16, pi-permuted cols) = [dinv[row] *] (A[n,K] @ W[K,128]).
// SCALE=false (layer 1, R22): store UNSCALED; agg applies dinv[src].
template<bool A32, bool SCALE>
__device__ __forceinline__ void gemm_body(int gblk, int tid,
                                          const void* __restrict__ Av,
                                          const _Float16* __restrict__ Bsw,
                                          _Float16* __restrict__ Cb,
                                          const float* __restrict__ dinv,
                                          int n, int K) {
    int w     = tid >> 6;
    int ln    = tid & 63;
    int lane16 = ln & 15;
    int quad  = ln >> 4;
    int mrow  = gblk * 64 + w * 16 + lane16;
    int mload = mrow < n ? mrow : n - 1;
    int nchunk = K >> 5;

    floatx4 acc[8];
    #pragma unroll
    for (int t = 0; t < 8; ++t) acc[t] = (floatx4){0.f, 0.f, 0.f, 0.f};

    for (int c = 0; c < nchunk; ++c) {
        half8 a;
        if constexpr (A32) {
            const float* ap = (const float*)Av + (size_t)mload * K + c * 32 + quad * 8;
            float4 v0 = *(const float4*)ap;
            float4 v1 = *(const float4*)(ap + 4);
            a[0] = (_Float16)v0.x; a[1] = (_Float16)v0.y;
            a[2] = (_Float16)v0.z; a[3] = (_Float16)v0.w;
            a[4] = (_Float16)v1.x; a[5] = (_Float16)v1.y;
            a[6] = (_Float16)v1.z; a[7] = (_Float16)v1.w;
        } else {
            const _Float16* ap = (const _Float16*)Av + (size_t)mload * K + c * 32 + quad * 8;
            a = *(const half8*)ap;
        }
        const _Float16* bp = Bsw + ((size_t)(c * 8) * 64 + ln) * 8;
        #pragma unroll
        for (int t = 0; t < 8; ++t) {
            half8 b = *(const half8*)(bp + (size_t)t * 512);
            acc[t] = __builtin_amdgcn_mfma_f32_16x16x32_f16(a, b, acc[t], 0, 0, 0);
        }
    }

    int rbase = gblk * 64 + w * 16 + quad * 4;
    #pragma unroll
    for (int r = 0; r < 4; ++r) {
        int R = rbase + r;
        if (R < n) {
            half8 o;
            if constexpr (SCALE) {
                float d = dinv[R];
                #pragma unroll
                for (int t = 0; t < 8; ++t) o[t] = (_Float16)(acc[t][r] * d);
            } else {
                #pragma unroll
                for (int t = 0; t < 8; ++t) o[t] = (_Float16)(acc[t][r]);
            }
            *(half8*)(Cb + (size_t)R * 128 + lane16 * 8) = o;
        }
    }
}

// Fused independent kernels (R22): block-range split, no inter-block coupling.
__global__ __launch_bounds__(256) void k_cg(const int* __restrict__ dst,
                                            int* __restrict__ rep,
                                            int* __restrict__ slot,
                                            const float* __restrict__ fts,
                                            const _Float16* __restrict__ Bsw1,
                                            _Float16* __restrict__ xwb,
                                            int nN, int e8, int e, int n,
                                            int nCnt, int gOff) {
    if ((int)blockIdx.x < nCnt)
        count_body(blockIdx.x, threadIdx.x, dst, rep, slot, nN, e8, e);
    else
        gemm_body<true, false>(blockIdx.x - nCnt + gOff, threadIdx.x,
                               fts, Bsw1, xwb, nullptr, n, IN_DIM);
}

__global__ __launch_bounds__(256) void k_fg(const int* __restrict__ src,
                                            const int* __restrict__ dst,
                                            const int* __restrict__ slot,
                                            const int* __restrict__ rep,
                                            int* __restrict__ col,
                                            const float* __restrict__ fts,
                                            const _Float16* __restrict__ Bsw1,
                                            _Float16* __restrict__ xwb,
                                            int nN, int e8, int e, int n,
                                            int nFill, int gOff) {
    if ((int)blockIdx.x < nFill)
        fill_body(blockIdx.x, threadIdx.x, src, dst, slot, rep, col, nN, e8, e);
    else
        gemm_body<true, false>(blockIdx.x - nFill + gOff, threadIdx.x,
                               fts, Bsw1, xwb, nullptr, n, IN_DIM);
}

// Layer-2 GEMM (standalone, dinv pre-scaled as before).
__global__ __launch_bounds__(256) void k_gemm2(const _Float16* __restrict__ Av,
                                               const _Float16* __restrict__ Bsw,
                                               _Float16* __restrict__ Cb,
                                               const float* __restrict__ dinv,
                                               int n) {
    gemm_body<false, true>(blockIdx.x, threadIdx.x, Av, Bsw, Cb, dinv, n, HID);
}

// Merged scan (R21): plane offsets in regs -> LDS scan of node totals ->
// block base via atomic ticket -> write row_beg/row_end/dinv + baked planes.
__global__ __launch_bounds__(SCAN_B) void k_scan(int* __restrict__ rep,
                                                 int* __restrict__ row_beg,
                                                 int* __restrict__ row_end,
                                                 float* __restrict__ dinv,
                                                 int* __restrict__ gtick,
                                                 int nN, int n) {
    __shared__ int tmp[SCAN_B];
    __shared__ int sbase;
    int tid = threadIdx.x;
    int i = blockIdx.x * SCAN_B + tid;
    int off[NREP];
    int c = 0;
    if (i < n) {
        #pragma unroll
        for (int r = 0; r < NREP; ++r) {
            int t = rep[r * nN + i];
            off[r] = c;
            c += t;
        }
    }
    tmp[tid] = c;
    __syncthreads();
    #pragma unroll
    for (int o = 1; o < SCAN_B; o <<= 1) {
        int v = (tid >= o) ? tmp[tid - o] : 0;
        __syncthreads();
        tmp[tid] += v;
        __syncthreads();
    }
    if (tid == SCAN_B - 1) sbase = atomicAdd(gtick, tmp[tid]);
    __syncthreads();
    int base = sbase;
    if (i < n) {
        int rp = base + tmp[tid] - c;
        row_beg[i] = rp;
        row_end[i] = rp + c;
        dinv[i] = rsqrtf((float)(c + 1));   // +1 self-loop
        #pragma unroll
        for (int r = 0; r < NREP; ++r) rep[r * nN + i] = off[r] + rp;
    }
}

// One wave per node. NPW=1 (agg1, max TLP) / NPW=4 (agg2, WcT amortized).
// SCALED (agg1, R22): xwb is UNSCALED; dinv[src] is the fma_mix scale,
// di scales the self term. !SCALED (agg2): xwb pre-scaled, scale=1.0f.
// 16 lanes per row (dwordx4), 4 edges/load instr x4 unroll; col prefetch
// (R13); remainder unroll-2 (R16); shfl_xor(16,32) group combine.
// CLS: WcT[c][k] (132-padded) in LDS once per block; h2 row via per-wave
// LDS; lane computes out[c=pos] over grp's 32-k slice then TWO shfl_xor.
template<bool OUT16, bool CLS, int NPW, bool SCALED>
__global__ __launch_bounds__(256) void k_agg(const _Float16* __restrict__ xwb,
                                             const float* __restrict__ dinv,
                                             const int* __restrict__ row_beg,
                                             const int* __restrict__ row_end,
                                             const int* __restrict__ col,
                                             const float* __restrict__ bp,
                                             void* __restrict__ hout,
                                             const float* __restrict__ Wc,
                                             const float* __restrict__ bc,
                                             float* __restrict__ outp,
                                             int n) {
    __shared__ float WcT[CLS ? 16 * 132 : 1];
    __shared__ float h2s[CLS ? 4 * 128 : 1];

    int wave = threadIdx.x >> 6;
    int ln   = threadIdx.x & 63;
    int grp  = ln >> 4;
    int pos  = ln & 15;

    if constexpr (CLS) {
        for (int t = threadIdx.x; t < 128 * OUT_DIM; t += 256) {
            int k = t >> 4, c = t & 15;
            WcT[c * 132 + k] = Wc[t];
        }
        __syncthreads();
    }

    const _Float16* xb = xwb + pos * 8;
    float onef = 1.0f;

    float4 bq0 = *(const float4*)(bp + pos * 8);
    float4 bq1 = *(const float4*)(bp + pos * 8 + 4);
    float bb[8] = {bq0.x, bq0.y, bq0.z, bq0.w, bq1.x, bq1.y, bq1.z, bq1.w};
    float bcv = 0.f;
    if constexpr (CLS) bcv = bc[pos];

    int i0 = (blockIdx.x * 4 + wave) * NPW;
    if (i0 >= n) return;
    int ecarry = row_beg[i0];

    #pragma unroll 1
    for (int it = 0; it < NPW; ++it) {
        int i = i0 + it;
        if (NPW > 1 && i >= n) break;
        int e0 = ecarry;
        int e1 = row_end[i];
        ecarry = e1;

        uint4 usu = *(const uint4*)(xb + (size_t)i * 128);
        float di  = dinv[i];

        float acc[8];
        #pragma unroll
        for (int j = 0; j < 8; ++j) acc[j] = 0.f;

        int e = e0 + grp;
        if (e + 12 < e1) {
            int s0 = col[e], s1 = col[e + 4], s2 = col[e + 8], s3 = col[e + 12];
            while (true) {
                int en = e + 16;
                bool more = (en + 12 < e1);
                int t0, t1, t2, t3;
                if (more) {
                    t0 = col[en]; t1 = col[en + 4]; t2 = col[en + 8]; t3 = col[en + 12];
                }
                float w0 = onef, w1 = onef, w2 = onef, w3 = onef;
                if constexpr (SCALED) {
                    w0 = dinv[s0]; w1 = dinv[s1]; w2 = dinv[s2]; w3 = dinv[s3];
                }
                uint4 u0 = *(const uint4*)(xb + (size_t)s0 * 128);
                uint4 u1 = *(const uint4*)(xb + (size_t)s1 * 128);
                uint4 u2 = *(const uint4*)(xb + (size_t)s2 * 128);
                uint4 u3 = *(const uint4*)(xb + (size_t)s3 * 128);
                accum8(acc, u0, w0);
                accum8(acc, u1, w1);
                accum8(acc, u2, w2);
                accum8(acc, u3, w3);
                e = en;
                if (!more) break;
                s0 = t0; s1 = t1; s2 = t2; s3 = t3;
            }
        }
        for (; e + 4 < e1; e += 8) {
            int sa = col[e], sb = col[e + 4];
            float wa = onef, wb = onef;
            if constexpr (SCALED) { wa = dinv[sa]; wb = dinv[sb]; }
            uint4 ua = *(const uint4*)(xb + (size_t)sa * 128);
            uint4 ub = *(const uint4*)(xb + (size_t)sb * 128);
            accum8(acc, ua, wa);
            accum8(acc, ub, wb);
        }
        if (e < e1) {
            int s = col[e];
            float ws = onef;
            if constexpr (SCALED) ws = dinv[s];
            uint4 u = *(const uint4*)(xb + (size_t)s * 128);
            accum8(acc, u, ws);
        }

        #pragma unroll
        for (int j = 0; j < 8; ++j) {
            acc[j] += __shfl_xor(acc[j], 16, 64);
            acc[j] += __shfl_xor(acc[j], 32, 64);
        }

        // self-loop: scale di when xwb unscaled, 1.0 when pre-scaled
        accum8(acc, usu, SCALED ? di : onef);

        float ov[8];
        #pragma unroll
        for (int j = 0; j < 8; ++j)
            ov[j] = fmaxf(fmaf(di, acc[j], bb[j]), 0.f);

        if constexpr (OUT16) {
            if (grp == 0) {
                half8 o;
                #pragma unroll
                for (int j = 0; j < 8; ++j) o[j] = (_Float16)ov[j];
                *(half8*)((_Float16*)hout + (size_t)i * 128 + pos * 8) = o;
            }
        } else {
            float* hf = (float*)hout + (size_t)i * 128;
            #pragma unroll
            for (int h = 0; h < 2; ++h) {
                int j = 2 * grp + h;
                hf[j * 16 + pos] = ov[j];
                if constexpr (CLS) h2s[wave * 128 + j * 16 + pos] = ov[j];
            }
        }

        if constexpr (CLS) {
            const float* wrow = &WcT[pos * 132 + grp * 32];
            const float* hrow = &h2s[wave * 128 + grp * 32];
            float pt = 0.f;
            #pragma unroll
            for (int kk = 0; kk < 32; kk += 4) {
                float4 wv = *(const float4*)(wrow + kk);
                float4 hv = *(const float4*)(hrow + kk);
                pt = fmaf(hv.x, wv.x, pt);
                pt = fmaf(hv.y, wv.y, pt);
                pt = fmaf(hv.z, wv.z, pt);
                pt = fmaf(hv.w, wv.w, pt);
            }
            pt += __shfl_xor(pt, 16, 64);
            pt += __shfl_xor(pt, 32, 64);
            if (grp == 0) outp[(size_t)i * OUT_DIM + pos] = pt + bcv;
        }
    }
}

static inline size_t align256(size_t x) { return (x + 255) & ~(size_t)255; }

extern "C" void kernel_launch(void* const* d_in, const int* in_sizes, int n_in,
                              void* d_out, int out_size, void* d_ws, size_t ws_size,
                              hipStream_t stream) {
    const float* fts = (const float*)d_in[0];
    const int*   ei  = (const int*)d_in[1];
    const float* W1  = (const float*)d_in[2];
    const float* b1  = (const float*)d_in[3];
    const float* W2  = (const float*)d_in[4];
    const float* b2  = (const float*)d_in[5];
    const float* Wc  = (const float*)d_in[6];
    const float* bc  = (const float*)d_in[7];

    const int N = in_sizes[0] / IN_DIM;     // 50000
    const int E = in_sizes[1] / 2;          // 800000
    const int* src = ei;
    const int* dst = ei + E;

    char* p = (char*)d_ws;
    int* rep      = (int*)p;               p += align256(sizeof(int) * NREP * N);
    int* row_beg  = (int*)p;               p += align256(sizeof(int) * N);
    int* row_end  = (int*)p;               p += align256(sizeof(int) * N);
    float* dinv   = (float*)p;             p += align256(sizeof(float) * N);
    int* slot     = (int*)p;               p += align256(sizeof(int) * E);
    int* col      = (int*)p;               p += align256(sizeof(int) * (E + 16));
    int* gtick    = (int*)p;               p += align256(sizeof(int) * 16);
    _Float16* Bsw1 = (_Float16*)p;         p += align256(sizeof(_Float16) * IN_DIM * HID);
    _Float16* Bsw2 = (_Float16*)p;         p += align256(sizeof(_Float16) * HID * HID);
    float* bp1    = (float*)p;             p += align256(sizeof(float) * HID);
    float* bp2    = (float*)p;             p += align256(sizeof(float) * HID);
    _Float16* xwb = (_Float16*)p;          p += align256(sizeof(_Float16) * (size_t)N * HID);
    _Float16* h1  = (_Float16*)p;          p += align256(sizeof(_Float16) * (size_t)N * HID);

    float* out = (float*)d_out;                   // [N,16]
    float* h2  = (float*)d_out + (size_t)N * 16;  // [N,128]

    const int T = 256;
    const int E8 = E / 8;
    const int nCnt  = (E8 + T - 1) / T;          // 391 count/fill blocks
    const int nScanB = (N + SCAN_B - 1) / SCAN_B;
    const int G  = (N + 63) / 64;                // 782 gemm1 blocks
    const int G1 = G / 2;                        // half with count
    const int G2 = G - G1;                       // half with fill

    // Fused prep (rep+ticket zero + W swizzles + bias perms)
    const int nrepN = NREP * N;
    const int zr = (nrepN >> 2) + (nrepN & 3);
    const int prepTot = zr + IN_DIM * HID + HID * HID + 2 * HID;
    k_prep<<<(prepTot + T - 1) / T, T, 0, stream>>>(rep, nrepN, gtick, W1, Bsw1, W2, Bsw2,
                                                    b1, bp1, b2, bp2);
    // count || gemm1 first half (independent: gemm1 needs only Bsw1)
    k_cg<<<nCnt + G1, T, 0, stream>>>(dst, rep, slot, fts, Bsw1, xwb,
                                      N, E8, E, N, nCnt, 0);
    // merged scan
    k_scan<<<nScanB, SCAN_B, 0, stream>>>(rep, row_beg, row_end, dinv, gtick, N, N);
    // fill || gemm1 second half
    k_fg<<<nCnt + G2, T, 0, stream>>>(src, dst, slot, rep, col, fts, Bsw1, xwb,
                                      N, E8, E, N, nCnt, G1);

    dim3 gAgg1((N + 3) / 4);            // NPW=1: 12500 blocks (max TLP)
    dim3 gAgg2((N + 15) / 16);          // NPW=4: 3125 blocks (amortized CLS)

    // Layer 1 aggregation (SCALED: applies dinv[src] in the accumulate)
    k_agg<true, false, 1, true><<<gAgg1, T, 0, stream>>>(xwb, dinv, row_beg, row_end,
                                                         col, bp1, h1,
                                                         nullptr, nullptr, nullptr, N);
    // Layer 2
    k_gemm2<<<G, T, 0, stream>>>(h1, Bsw2, xwb, dinv, N);
    // Aggregation + fused classifier
    k_agg<false, true, 4, false><<<gAgg2, T, 0, stream>>>(xwb, dinv, row_beg, row_end,
                                                          col, bp2, h2, Wc, bc, out, N);
}

// Round 14
// 253.267 us; speedup vs baseline: 1.0164x; 1.0164x over previous
//
#include <hip/hip_runtime.h>

// ---------------------------------------------------------------------------
// GCN: x1 = relu(Ahat @ (fts@W1) + b1); x2 = relu(Ahat @ (x1@W2) + b2);
//      out = x2@Wc + bc.  Ahat = D^-1/2 (A + I) D^-1/2.
// d_out = [out (N*16) | x2 (N*128)] fp32.
// R2-R13: scan/gather/MFMA/slot-capture/8-replica/fma_mix ladder.
// R10,R14/15,R18/19,R20,R22 ALL FAILED the same way: static partitions,
//      manual prefetch, and concurrent-kernel fusion each stole TLP from
//      latency-bound phases. RULE: every phase here wants the whole
//      machine; give the HW scheduler many small independent blocks.
// R16/R17: NPW=4 (agg2) / NPW=1 (agg1). 257.0us.
// R21: merged scan via atomic block-ticket. 253.3us BEST.
// R22 FAILED: count||gemm1 fusion -> count stretched 47.6us (occupancy 21%,
//      VGPR 48 forced on count blocks). Reverted.
// R23: R21 + packed row extents. R21's split row_beg/row_end cost agg2
//      +1.6us (two scattered load streams per node). rbe[i]=int2{beg,end}
//      = ONE 8B load per node; ecarry chain dropped. Both aggs benefit.
// ---------------------------------------------------------------------------

#define IN_DIM 256
#define HID 128
#define OUT_DIM 16
#define SCAN_B 256
#define NREP 8

typedef _Float16 half8  __attribute__((ext_vector_type(8)));
typedef float    floatx4 __attribute__((ext_vector_type(4)));

// acc[0..7] += fp16 elements of u (4 dwords, lo/hi halves), exact, 1 VALU each.
__device__ __forceinline__ void accum8(float* acc, uint4 u, float onef) {
    asm("v_fma_mix_f32 %0, %1, %2, %0 op_sel:[0,0,0] op_sel_hi:[1,0,0]"
        : "+v"(acc[0]) : "v"(u.x), "v"(onef));
    asm("v_fma_mix_f32 %0, %1, %2, %0 op_sel:[1,0,0] op_sel_hi:[1,0,0]"
        : "+v"(acc[1]) : "v"(u.x), "v"(onef));
    asm("v_fma_mix_f32 %0, %1, %2, %0 op_sel:[0,0,0] op_sel_hi:[1,0,0]"
        : "+v"(acc[2]) : "v"(u.y), "v"(onef));
    asm("v_fma_mix_f32 %0, %1, %2, %0 op_sel:[1,0,0] op_sel_hi:[1,0,0]"
        : "+v"(acc[3]) : "v"(u.y), "v"(onef));
    asm("v_fma_mix_f32 %0, %1, %2, %0 op_sel:[0,0,0] op_sel_hi:[1,0,0]"
        : "+v"(acc[4]) : "v"(u.z), "v"(onef));
    asm("v_fma_mix_f32 %0, %1, %2, %0 op_sel:[1,0,0] op_sel_hi:[1,0,0]"
        : "+v"(acc[5]) : "v"(u.z), "v"(onef));
    asm("v_fma_mix_f32 %0, %1, %2, %0 op_sel:[0,0,0] op_sel_hi:[1,0,0]"
        : "+v"(acc[6]) : "v"(u.w), "v"(onef));
    asm("v_fma_mix_f32 %0, %1, %2, %0 op_sel:[1,0,0] op_sel_hi:[1,0,0]"
        : "+v"(acc[7]) : "v"(u.w), "v"(onef));
}

__device__ __forceinline__ void wswz_one(const float* W, _Float16* Bsw, int o, int permK) {
    int j    = o & 7;
    int lane = (o >> 3) & 63;
    int t    = (o >> 9) & 7;
    int c    = o >> 12;
    int k = c * 32 + ((lane >> 4) << 3) + j;
    if (permK) k = ((k & 7) << 4) + (k >> 3);
    int ncol = t * 16 + (lane & 15);
    Bsw[o] = (_Float16)W[k * 128 + ncol];
}

// Fused prep: zero rep planes + ticket; swizzle W1,W2; permute biases.
__global__ void k_prep(int* __restrict__ rep, int nrepN, int* __restrict__ gtick,
                       const float* __restrict__ W1, _Float16* __restrict__ Bsw1,
                       const float* __restrict__ W2, _Float16* __restrict__ Bsw2,
                       const float* __restrict__ b1, float* __restrict__ bp1,
                       const float* __restrict__ b2, float* __restrict__ bp2) {
    int t = blockIdx.x * blockDim.x + threadIdx.x;
    if (t == 0) gtick[0] = 0;
    int z4 = nrepN >> 2;
    int zr = z4 + (nrepN & 3);
    if (t < z4) { ((int4*)rep)[t] = make_int4(0, 0, 0, 0); return; }
    if (t < zr) { rep[4 * z4 + (t - z4)] = 0; return; }
    int o = t - zr;
    if (o < IN_DIM * HID) { wswz_one(W1, Bsw1, o, 0); return; }
    o -= IN_DIM * HID;
    if (o < HID * HID) { wswz_one(W2, Bsw2, o, 1); return; }
    o -= HID * HID;
    if (o < HID) { bp1[o] = b1[((o & 7) << 4) + (o >> 3)]; return; }
    o -= HID;
    if (o < HID) { bp2[o] = b2[((o & 7) << 4) + (o >> 3)]; return; }
}

// Thread i owns edges 8i..8i+7; edge 8i+k bumps replica plane k.
__global__ void k_count(const int* __restrict__ dst, int* __restrict__ rep,
                        int* __restrict__ slot, int nN, int e8, int e) {
    int i = blockIdx.x * blockDim.x + threadIdx.x;
    if (i < e8) {
        int4 d0 = ((const int4*)dst)[2 * i];
        int4 d1 = ((const int4*)dst)[2 * i + 1];
        int4 s0, s1;
        s0.x = atomicAdd(&rep[0 * nN + d0.x], 1);
        s0.y = atomicAdd(&rep[1 * nN + d0.y], 1);
        s0.z = atomicAdd(&rep[2 * nN + d0.z], 1);
        s0.w = atomicAdd(&rep[3 * nN + d0.w], 1);
        s1.x = atomicAdd(&rep[4 * nN + d1.x], 1);
        s1.y = atomicAdd(&rep[5 * nN + d1.y], 1);
        s1.z = atomicAdd(&rep[6 * nN + d1.z], 1);
        s1.w = atomicAdd(&rep[7 * nN + d1.w], 1);
        ((int4*)slot)[2 * i]     = s0;
        ((int4*)slot)[2 * i + 1] = s1;
    }
    int base = e8 * 8;
    int t = blockIdx.x * blockDim.x + threadIdx.x;
    if (t < e - base) {
        int j = base + t;
        slot[j] = atomicAdd(&rep[(j & 7) * nN + dst[j]], 1);
    }
}

// Merged scan (R21): plane offsets in regs -> LDS scan of node totals ->
// block base via atomic ticket -> write rbe/dinv + baked planes.
// Bases are non-monotone across blocks (valid: ranges disjoint & exact).
__global__ __launch_bounds__(SCAN_B) void k_scan(int* __restrict__ rep,
                                                 int2* __restrict__ rbe,
                                                 float* __restrict__ dinv,
                                                 int* __restrict__ gtick,
                                                 int nN, int n) {
    __shared__ int tmp[SCAN_B];
    __shared__ int sbase;
    int tid = threadIdx.x;
    int i = blockIdx.x * SCAN_B + tid;
    int off[NREP];
    int c = 0;
    if (i < n) {
        #pragma unroll
        for (int r = 0; r < NREP; ++r) {
            int t = rep[r * nN + i];
            off[r] = c;
            c += t;
        }
    }
    tmp[tid] = c;
    __syncthreads();
    #pragma unroll
    for (int o = 1; o < SCAN_B; o <<= 1) {
        int v = (tid >= o) ? tmp[tid - o] : 0;
        __syncthreads();
        tmp[tid] += v;
        __syncthreads();
    }
    if (tid == SCAN_B - 1) sbase = atomicAdd(gtick, tmp[tid]);
    __syncthreads();
    int base = sbase;
    if (i < n) {
        int rp = base + tmp[tid] - c;
        rbe[i] = make_int2(rp, rp + c);     // packed extent: ONE 8B load in agg
        dinv[i] = rsqrtf((float)(c + 1));   // +1 self-loop
        #pragma unroll
        for (int r = 0; r < NREP; ++r) rep[r * nN + i] = off[r] + rp;
    }
}

// Atomic-free scatter: col[rep[k][dst] + slot] = src.
__global__ void k_fill(const int* __restrict__ src, const int* __restrict__ dst,
                       const int* __restrict__ slot, const int* __restrict__ rep,
                       int* __restrict__ col, int nN, int e8, int e) {
    int i = blockIdx.x * blockDim.x + threadIdx.x;
    if (i < e8) {
        int4 v0 = ((const int4*)src)[2 * i];
        int4 v1 = ((const int4*)src)[2 * i + 1];
        int4 d0 = ((const int4*)dst)[2 * i];
        int4 d1 = ((const int4*)dst)[2 * i + 1];
        int4 s0 = ((const int4*)slot)[2 * i];
        int4 s1 = ((const int4*)slot)[2 * i + 1];
        col[rep[0 * nN + d0.x] + s0.x] = v0.x;
        col[rep[1 * nN + d0.y] + s0.y] = v0.y;
        col[rep[2 * nN + d0.z] + s0.z] = v0.z;
        col[rep[3 * nN + d0.w] + s0.w] = v0.w;
        col[rep[4 * nN + d1.x] + s1.x] = v1.x;
        col[rep[5 * nN + d1.y] + s1.y] = v1.y;
        col[rep[6 * nN + d1.z] + s1.z] = v1.z;
        col[rep[7 * nN + d1.w] + s1.w] = v1.w;
    }
    int base = e8 * 8;
    int t = blockIdx.x * blockDim.x + threadIdx.x;
    if (t < e - base) {
        int j = base + t;
        col[rep[(j & 7) * nN + dst[j]] + slot[j]] = src[j];
    }
}

// Cb[n,128](fp16, pi-permuted cols) = dinv[row] * (A[n,K] @ W[K,128]).
template<bool A32>
__global__ __launch_bounds__(256) void k_gemm_mfma(const void* __restrict__ Av,
                                                   const _Float16* __restrict__ Bsw,
                                                   _Float16* __restrict__ Cb,
                                                   const float* __restrict__ dinv,
                                                   int n, int K) {
    int tid   = threadIdx.x;
    int w     = tid >> 6;
    int ln    = tid & 63;
    int lane16 = ln & 15;
    int quad  = ln >> 4;
    int mrow  = blockIdx.x * 64 + w * 16 + lane16;
    int mload = mrow < n ? mrow : n - 1;
    int nchunk = K >> 5;

    floatx4 acc[8];
    #pragma unroll
    for (int t = 0; t < 8; ++t) acc[t] = (floatx4){0.f, 0.f, 0.f, 0.f};

    for (int c = 0; c < nchunk; ++c) {
        half8 a;
        if constexpr (A32) {
            const float* ap = (const float*)Av + (size_t)mload * K + c * 32 + quad * 8;
            float4 v0 = *(const float4*)ap;
            float4 v1 = *(const float4*)(ap + 4);
            a[0] = (_Float16)v0.x; a[1] = (_Float16)v0.y;
            a[2] = (_Float16)v0.z; a[3] = (_Float16)v0.w;
            a[4] = (_Float16)v1.x; a[5] = (_Float16)v1.y;
            a[6] = (_Float16)v1.z; a[7] = (_Float16)v1.w;
        } else {
            const _Float16* ap = (const _Float16*)Av + (size_t)mload * K + c * 32 + quad * 8;
            a = *(const half8*)ap;
        }
        const _Float16* bp = Bsw + ((size_t)(c * 8) * 64 + ln) * 8;
        #pragma unroll
        for (int t = 0; t < 8; ++t) {
            half8 b = *(const half8*)(bp + (size_t)t * 512);
            acc[t] = __builtin_amdgcn_mfma_f32_16x16x32_f16(a, b, acc[t], 0, 0, 0);
        }
    }

    int rbase = blockIdx.x * 64 + w * 16 + quad * 4;
    #pragma unroll
    for (int r = 0; r < 4; ++r) {
        int R = rbase + r;
        if (R < n) {
            float d = dinv[R];
            half8 o;
            #pragma unroll
            for (int t = 0; t < 8; ++t) o[t] = (_Float16)(acc[t][r] * d);
            *(half8*)(Cb + (size_t)R * 128 + lane16 * 8) = o;
        }
    }
}

// One wave per node. NPW=1 (agg1, max TLP) / NPW=4 (agg2, WcT amortized).
// Extent = rbe[i] (packed int2, one 8B load per node -- R23).
// 16 lanes per row (dwordx4), 4 edges per load instr, x4 unroll = 16 rows in
// flight; col indices for iter t+1 prefetched (R13). v_fma_mix accumulate
// (exact). Remainder loop unroll-2, both gathers in flight (R16).
// shfl_xor(16,32) combines the 4 groups.
// Lane (grp,pos): features at stored positions pos*8..pos*8+7 = cols j*16+pos.
// CLS: WcT[c][k] (132-padded) in LDS once per block; h2 row via per-wave LDS;
// lane computes out[c=pos] over grp's 32-k slice then TWO shfl_xor.
template<bool OUT16, bool CLS, int NPW>
__global__ __launch_bounds__(256) void k_agg(const _Float16* __restrict__ xwb,
                                             const float* __restrict__ dinv,
                                             const int2* __restrict__ rbe,
                                             const int* __restrict__ col,
                                             const float* __restrict__ bp,
                                             void* __restrict__ hout,
                                             const float* __restrict__ Wc,
                                             const float* __restrict__ bc,
                                             float* __restrict__ outp,
                                             int n) {
    __shared__ float WcT[CLS ? 16 * 132 : 1];   // [c][k], pad 132 vs bank aliasing
    __shared__ float h2s[CLS ? 4 * 128 : 1];    // per-wave h2 row

    int wave = threadIdx.x >> 6;
    int ln   = threadIdx.x & 63;
    int grp  = ln >> 4;          // 0..3: which edge of each quad
    int pos  = ln & 15;          // 16B segment within the 256B row

    if constexpr (CLS) {
        // Wc[128][16] row-major -> WcT[c*132 + k]; coalesced global reads.
        for (int t = threadIdx.x; t < 128 * OUT_DIM; t += 256) {
            int k = t >> 4, c = t & 15;
            WcT[c * 132 + k] = Wc[t];
        }
        __syncthreads();         // before any early return (barrier safety)
    }

    const _Float16* xb = xwb + pos * 8;
    float onef = 1.0f;

    // ---- node-independent operands: once per wave ----
    float4 bq0 = *(const float4*)(bp + pos * 8);
    float4 bq1 = *(const float4*)(bp + pos * 8 + 4);
    float bb[8] = {bq0.x, bq0.y, bq0.z, bq0.w, bq1.x, bq1.y, bq1.z, bq1.w};
    float bcv = 0.f;
    if constexpr (CLS) bcv = bc[pos];

    int i0 = (blockIdx.x * 4 + wave) * NPW;
    if (i0 >= n) return;

    #pragma unroll 1
    for (int it = 0; it < NPW; ++it) {
        int i = i0 + it;
        if (NPW > 1 && i >= n) break;
        int2 ee = rbe[i];                // packed: one 8B load
        int e0 = ee.x, e1 = ee.y;

        // self-row + dinv issued before the gather chain
        uint4 usu = *(const uint4*)(xb + (size_t)i * 128);
        float di  = dinv[i];

        float acc[8];
        #pragma unroll
        for (int j = 0; j < 8; ++j) acc[j] = 0.f;

        int e = e0 + grp;
        if (e + 12 < e1) {
            int s0 = col[e], s1 = col[e + 4], s2 = col[e + 8], s3 = col[e + 12];
            while (true) {
                int en = e + 16;
                bool more = (en + 12 < e1);
                int t0, t1, t2, t3;
                if (more) {            // prefetch next quad's indices
                    t0 = col[en]; t1 = col[en + 4]; t2 = col[en + 8]; t3 = col[en + 12];
                }
                uint4 u0 = *(const uint4*)(xb + (size_t)s0 * 128);
                uint4 u1 = *(const uint4*)(xb + (size_t)s1 * 128);
                uint4 u2 = *(const uint4*)(xb + (size_t)s2 * 128);
                uint4 u3 = *(const uint4*)(xb + (size_t)s3 * 128);
                accum8(acc, u0, onef);
                accum8(acc, u1, onef);
                accum8(acc, u2, onef);
                accum8(acc, u3, onef);
                e = en;
                if (!more) break;
                s0 = t0; s1 = t1; s2 = t2; s3 = t3;
            }
        }
        // remainder: unroll-2, both gathers in flight (tail ILP)
        for (; e + 4 < e1; e += 8) {
            int sa = col[e], sb = col[e + 4];
            uint4 ua = *(const uint4*)(xb + (size_t)sa * 128);
            uint4 ub = *(const uint4*)(xb + (size_t)sb * 128);
            accum8(acc, ua, onef);
            accum8(acc, ub, onef);
        }
        if (e < e1) {
            int s = col[e];
            uint4 u = *(const uint4*)(xb + (size_t)s * 128);
            accum8(acc, u, onef);
        }

        // combine the 4 groups (lanes xor 16, xor 32)
        #pragma unroll
        for (int j = 0; j < 8; ++j) {
            acc[j] += __shfl_xor(acc[j], 16, 64);
            acc[j] += __shfl_xor(acc[j], 32, 64);
        }

        // self-loop (exact fp16->fp32 fma_mix adds)
        accum8(acc, usu, onef);

        float ov[8];
        #pragma unroll
        for (int j = 0; j < 8; ++j)
            ov[j] = fmaxf(fmaf(di, acc[j], bb[j]), 0.f);

        if constexpr (OUT16) {
            if (grp == 0) {
                half8 o;
                #pragma unroll
                for (int j = 0; j < 8; ++j) o[j] = (_Float16)ov[j];
                *(half8*)((_Float16*)hout + (size_t)i * 128 + pos * 8) = o;
            }
        } else {
            // position p = pos*8+j holds col j*16+pos; all-lane split: grp g
            // stores j=2g,2g+1 -> 2 stores/lane, wave covers the 512B row.
            float* hf = (float*)hout + (size_t)i * 128;
            #pragma unroll
            for (int h = 0; h < 2; ++h) {
                int j = 2 * grp + h;
                hf[j * 16 + pos] = ov[j];
                if constexpr (CLS) h2s[wave * 128 + j * 16 + pos] = ov[j];
            }
        }

        if constexpr (CLS) {
            // out[i][c=pos] = sum_k h2[k] * WcT[pos][k] + bc[pos];
            // lane covers k = grp*32 .. grp*32+31, then reduce over grp.
            // (wave-private LDS: ds ordering within the wave, no barrier)
            const float* wrow = &WcT[pos * 132 + grp * 32];
            const float* hrow = &h2s[wave * 128 + grp * 32];   // broadcast reads
            float pt = 0.f;
            #pragma unroll
            for (int kk = 0; kk < 32; kk += 4) {
                float4 wv = *(const float4*)(wrow + kk);
                float4 hv = *(const float4*)(hrow + kk);
                pt = fmaf(hv.x, wv.x, pt);
                pt = fmaf(hv.y, wv.y, pt);
                pt = fmaf(hv.z, wv.z, pt);
                pt = fmaf(hv.w, wv.w, pt);
            }
            pt += __shfl_xor(pt, 16, 64);
            pt += __shfl_xor(pt, 32, 64);
            if (grp == 0) outp[(size_t)i * OUT_DIM + pos] = pt + bcv;
        }
    }
}

static inline size_t align256(size_t x) { return (x + 255) & ~(size_t)255; }

extern "C" void kernel_launch(void* const* d_in, const int* in_sizes, int n_in,
                              void* d_out, int out_size, void* d_ws, size_t ws_size,
                              hipStream_t stream) {
    const float* fts = (const float*)d_in[0];
    const int*   ei  = (const int*)d_in[1];
    const float* W1  = (const float*)d_in[2];
    const float* b1  = (const float*)d_in[3];
    const float* W2  = (const float*)d_in[4];
    const float* b2  = (const float*)d_in[5];
    const float* Wc  = (const float*)d_in[6];
    const float* bc  = (const float*)d_in[7];

    const int N = in_sizes[0] / IN_DIM;     // 50000
    const int E = in_sizes[1] / 2;          // 800000
    const int* src = ei;
    const int* dst = ei + E;

    char* p = (char*)d_ws;
    int* rep      = (int*)p;               p += align256(sizeof(int) * NREP * N);
    int2* rbe     = (int2*)p;              p += align256(sizeof(int2) * N);
    float* dinv   = (float*)p;             p += align256(sizeof(float) * N);
    int* slot     = (int*)p;               p += align256(sizeof(int) * E);
    int* col      = (int*)p;               p += align256(sizeof(int) * (E + 16));
    int* gtick    = (int*)p;               p += align256(sizeof(int) * 16);
    _Float16* Bsw1 = (_Float16*)p;         p += align256(sizeof(_Float16) * IN_DIM * HID);
    _Float16* Bsw2 = (_Float16*)p;         p += align256(sizeof(_Float16) * HID * HID);
    float* bp1    = (float*)p;             p += align256(sizeof(float) * HID);
    float* bp2    = (float*)p;             p += align256(sizeof(float) * HID);
    _Float16* xwb = (_Float16*)p;          p += align256(sizeof(_Float16) * (size_t)N * HID);
    _Float16* h1  = (_Float16*)p;          p += align256(sizeof(_Float16) * (size_t)N * HID);

    float* out = (float*)d_out;                   // [N,16]
    float* h2  = (float*)d_out + (size_t)N * 16;  // [N,128]

    const int T = 256;
    const int E8 = E / 8;
    dim3 gE8((E8 + T - 1) / T);
    const int nScanB = (N + SCAN_B - 1) / SCAN_B;

    // Fused prep (rep+ticket zero + W swizzles + bias perms)
    const int nrepN = NREP * N;
    const int zr = (nrepN >> 2) + (nrepN & 3);
    const int prepTot = zr + IN_DIM * HID + HID * HID + 2 * HID;
    k_prep<<<(prepTot + T - 1) / T, T, 0, stream>>>(rep, nrepN, gtick, W1, Bsw1, W2, Bsw2,
                                                    b1, bp1, b2, bp2);
    // Graph structure (count -> merged scan -> fill)
    k_count<<<gE8, T, 0, stream>>>(dst, rep, slot, N, E8, E);
    k_scan<<<nScanB, SCAN_B, 0, stream>>>(rep, rbe, dinv, gtick, N, N);
    k_fill<<<gE8, T, 0, stream>>>(src, dst, slot, rep, col, N, E8, E);

    dim3 gGemm((N + 63) / 64);
    dim3 gAgg1((N + 3) / 4);            // NPW=1: 12500 blocks (max TLP)
    dim3 gAgg2((N + 15) / 16);          // NPW=4: 3125 blocks (amortized CLS)

    // Layer 1
    k_gemm_mfma<true><<<gGemm, T, 0, stream>>>(fts, Bsw1, xwb, dinv, N, IN_DIM);
    k_agg<true, false, 1><<<gAgg1, T, 0, stream>>>(xwb, dinv, rbe, col, bp1, h1,
                                                   nullptr, nullptr, nullptr, N);
    // Layer 2
    k_gemm_mfma<false><<<gGemm, T, 0, stream>>>(h1, Bsw2, xwb, dinv, N, HID);
    // Aggregation + fused classifier
    k_agg<false, true, 4><<<gAgg2, T, 0, stream>>>(xwb, dinv, rbe, col, bp2, h2,
                                                   Wc, bc, out, N);
}